// Round 1
// baseline (197.774 us; speedup 1.0000x reference)
//
#include <hip/hip_runtime.h>
#include <hip/hip_bf16.h>
#include <math.h>

// Problem constants (from reference)
#define NUM_EXPERTS 64
#define HIDDEN      4096
#define TOP_K       2
#define T_TOKENS    16384   // B*S = 4*4096

// Tiling
#define TOK_TILE 64
#define HC       64
#define LDPAD    68          // LDS leading dim (64 + 4 pad) to break bank conflicts

__global__ __launch_bounds__(256) void router_topk_kernel(
    const float* __restrict__ A,   // [T, H] hidden_states
    const float* __restrict__ W,   // [E, H] router weights
    float* __restrict__ out)       // [T*2] scores then [T*2] indices-as-float
{
    __shared__ float smem[2 * TOK_TILE * LDPAD];
    float* sA = smem;                       // [64][68]
    float* sW = smem + TOK_TILE * LDPAD;    // [64][68]

    const int tid = threadIdx.x;
    const int tg  = tid & 15;   // token-thread 0..15
    const int eg  = tid >> 4;   // expert-group 0..15
    const int tok0 = blockIdx.x * TOK_TILE;

    float acc[4][4];
#pragma unroll
    for (int k = 0; k < 4; ++k)
#pragma unroll
        for (int j = 0; j < 4; ++j) acc[k][j] = 0.0f;

    const int col   = (tid & 15) * 4;  // staging column (float4)
    const int rbase = tid >> 4;        // staging row base

    for (int h0 = 0; h0 < HIDDEN; h0 += HC) {
        // ---- stage A tile [64 tokens][64 h] and W tile [64 experts][64 h] ----
#pragma unroll
        for (int rp = 0; rp < 4; ++rp) {
            int row = rp * 16 + rbase;
            float4 va = *reinterpret_cast<const float4*>(
                &A[(size_t)(tok0 + row) * HIDDEN + h0 + col]);
            *reinterpret_cast<float4*>(&sA[row * LDPAD + col]) = va;
            float4 vw = *reinterpret_cast<const float4*>(
                &W[(size_t)row * HIDDEN + h0 + col]);
            *reinterpret_cast<float4*>(&sW[row * LDPAD + col]) = vw;
        }
        __syncthreads();

        // ---- compute: 4 tokens x 4 experts per thread, vectorized over h ----
#pragma unroll
        for (int hh = 0; hh < HC; hh += 4) {
            float4 a0 = *reinterpret_cast<const float4*>(&sA[(tg + 0)  * LDPAD + hh]);
            float4 a1 = *reinterpret_cast<const float4*>(&sA[(tg + 16) * LDPAD + hh]);
            float4 a2 = *reinterpret_cast<const float4*>(&sA[(tg + 32) * LDPAD + hh]);
            float4 a3 = *reinterpret_cast<const float4*>(&sA[(tg + 48) * LDPAD + hh]);
            float4 w0 = *reinterpret_cast<const float4*>(&sW[(eg * 4 + 0) * LDPAD + hh]);
            float4 w1 = *reinterpret_cast<const float4*>(&sW[(eg * 4 + 1) * LDPAD + hh]);
            float4 w2 = *reinterpret_cast<const float4*>(&sW[(eg * 4 + 2) * LDPAD + hh]);
            float4 w3 = *reinterpret_cast<const float4*>(&sW[(eg * 4 + 3) * LDPAD + hh]);

            const float4 av[4] = {a0, a1, a2, a3};
            const float4 wv[4] = {w0, w1, w2, w3};
#pragma unroll
            for (int k = 0; k < 4; ++k) {
#pragma unroll
                for (int j = 0; j < 4; ++j) {
                    acc[k][j] = fmaf(av[k].x, wv[j].x, acc[k][j]);
                    acc[k][j] = fmaf(av[k].y, wv[j].y, acc[k][j]);
                    acc[k][j] = fmaf(av[k].z, wv[j].z, acc[k][j]);
                    acc[k][j] = fmaf(av[k].w, wv[j].w, acc[k][j]);
                }
            }
        }
        __syncthreads();
    }

    // ---- epilogue: materialize logits [64][65] in LDS, then top-2 per token ----
    float* L = smem;  // 64*65 = 4160 floats, fits in sA region (64*68)
#pragma unroll
    for (int k = 0; k < 4; ++k) {
#pragma unroll
        for (int j = 0; j < 4; ++j) {
            L[(tg + 16 * k) * 65 + (eg * 4 + j)] = acc[k][j];
        }
    }
    __syncthreads();

    if (tid < TOK_TILE) {
        const float* row = &L[tid * 65];
        float best1 = -INFINITY, best2 = -INFINITY;
        int i1 = 0, i2 = 0;
#pragma unroll
        for (int e = 0; e < NUM_EXPERTS; ++e) {
            float v = row[e];
            if (v > best1) {
                best2 = best1; i2 = i1;
                best1 = v;     i1 = e;
            } else if (v > best2) {
                best2 = v; i2 = e;
            }
        }
        const int t = tok0 + tid;
        out[(size_t)t * 2 + 0] = best1;
        out[(size_t)t * 2 + 1] = best2;
        out[(size_t)T_TOKENS * 2 + (size_t)t * 2 + 0] = (float)i1;
        out[(size_t)T_TOKENS * 2 + (size_t)t * 2 + 1] = (float)i2;
    }
}

extern "C" void kernel_launch(void* const* d_in, const int* in_sizes, int n_in,
                              void* d_out, int out_size, void* d_ws, size_t ws_size,
                              hipStream_t stream) {
    const float* A = (const float*)d_in[0];   // hidden_states [4,4096,4096] fp32
    const float* W = (const float*)d_in[1];   // W [64,4096] fp32
    float* out = (float*)d_out;               // scores [16384*2] ++ indices [16384*2]

    dim3 grid(T_TOKENS / TOK_TILE);  // 256 blocks
    dim3 block(256);
    router_topk_kernel<<<grid, block, 0, stream>>>(A, W, out);
}

// Round 3
// 151.655 us; speedup vs baseline: 1.3041x; 1.3041x over previous
//
#include <hip/hip_runtime.h>
#include <hip/hip_bf16.h>
#include <math.h>

#define NUM_EXPERTS 64
#define HIDDEN      4096
#define T_TOKENS    16384   // B*S = 4*4096
#define BM 64               // tokens per block
#define BK 64               // k per chunk (2 MFMA k-steps)
#define NCHUNK (HIDDEN / BK)

using short8 = __attribute__((ext_vector_type(8))) short;   // 8 bf16 = 4 VGPRs
using f32x4  = __attribute__((ext_vector_type(4))) float;

// Round f32 -> bf16 bits (round-to-nearest-even), pure integer ops.
__device__ __forceinline__ unsigned bf16_rn(float f) {
    unsigned u = __builtin_bit_cast(unsigned, f);
    return (u + 0x7fffu + ((u >> 16) & 1u)) >> 16;
}

// Split (f0,f1) into packed bf16 hi parts (f0 in low 16) and bf16 lo parts.
__device__ __forceinline__ unsigned pack_pair(float f0, float f1, unsigned& lopk) {
    unsigned h0b = bf16_rn(f0);
    unsigned h1b = bf16_rn(f1);
    float h0 = __builtin_bit_cast(float, h0b << 16);
    float h1 = __builtin_bit_cast(float, h1b << 16);
    lopk = bf16_rn(f0 - h0) | (bf16_rn(f1 - h1) << 16);
    return h0b | (h1b << 16);
}

// 8 consecutive-k floats -> 16B hi plane + 16B lo plane
__device__ __forceinline__ void split8(const float4 a, const float4 b, uint4& hi, uint4& lo) {
    hi.x = pack_pair(a.x, a.y, lo.x);
    hi.y = pack_pair(a.z, a.w, lo.y);
    hi.z = pack_pair(b.x, b.y, lo.z);
    hi.w = pack_pair(b.z, b.w, lo.w);
}

#define MFMA(a, b, c) __builtin_amdgcn_mfma_f32_16x16x32_bf16((a), (b), (c), 0, 0, 0)

__global__ __launch_bounds__(256) void router_mfma_topk(
    const float* __restrict__ A,   // [T, H] fp32
    const float* __restrict__ W,   // [E, H] fp32
    float* __restrict__ out)       // scores [T*2] ++ indices-as-float [T*2]
{
    // LDS: two buffers of {A_hi 8K | A_lo 8K | W_hi 8K | W_lo 8K} = 32 KB each.
    // Fragment-ordered: plane byte offset = ((tile*2 + c)*64 + lane)*16.
    __shared__ unsigned char smem[65536];

    const int tid  = threadIdx.x;
    const int lane = tid & 63;
    const int tok0 = blockIdx.x * BM;

    // ---- staging decode: thread owns slot s0 = tid (tiles 0-1) and s0+256 (tiles 2-3)
    const int l0   = tid & 63;
    const int c0   = (tid >> 6) & 1;
    const int t0   = (tid >> 7) & 1;             // tile 0..1 (slot1 adds +2)
    const int row0 = t0 * 16 + (l0 & 15);        // 0..31 ; slot1 row = row0+32
    const int kk0  = c0 * 32 + ((l0 >> 4) & 3) * 8;
    const int slot0 = ((t0 * 2 + c0) * 64 + l0) * 16;  // byte offset; slot1 = +4096

    const size_t gA0 = (size_t)(tok0 + row0) * HIDDEN + kk0;
    const size_t gA1 = gA0 + (size_t)32 * HIDDEN;
    const size_t gW0 = (size_t)row0 * HIDDEN + kk0;
    const size_t gW1 = gW0 + (size_t)32 * HIDDEN;

    float4 rA0a, rA0b, rA1a, rA1b, rW0a, rW0b, rW1a, rW1b;

    auto load_regs = [&](int k0) {
        rA0a = *reinterpret_cast<const float4*>(A + gA0 + k0);
        rA0b = *reinterpret_cast<const float4*>(A + gA0 + k0 + 4);
        rA1a = *reinterpret_cast<const float4*>(A + gA1 + k0);
        rA1b = *reinterpret_cast<const float4*>(A + gA1 + k0 + 4);
        rW0a = *reinterpret_cast<const float4*>(W + gW0 + k0);
        rW0b = *reinterpret_cast<const float4*>(W + gW0 + k0 + 4);
        rW1a = *reinterpret_cast<const float4*>(W + gW1 + k0);
        rW1b = *reinterpret_cast<const float4*>(W + gW1 + k0 + 4);
    };

    auto write_buf = [&](int b) {
        unsigned char* base = smem + b * 32768;
        uint4 hi, lo;
        split8(rA0a, rA0b, hi, lo);
        *reinterpret_cast<uint4*>(base +     0 + slot0) = hi;
        *reinterpret_cast<uint4*>(base +  8192 + slot0) = lo;
        split8(rA1a, rA1b, hi, lo);
        *reinterpret_cast<uint4*>(base +     0 + slot0 + 4096) = hi;
        *reinterpret_cast<uint4*>(base +  8192 + slot0 + 4096) = lo;
        split8(rW0a, rW0b, hi, lo);
        *reinterpret_cast<uint4*>(base + 16384 + slot0) = hi;
        *reinterpret_cast<uint4*>(base + 24576 + slot0) = lo;
        split8(rW1a, rW1b, hi, lo);
        *reinterpret_cast<uint4*>(base + 16384 + slot0 + 4096) = hi;
        *reinterpret_cast<uint4*>(base + 24576 + slot0 + 4096) = lo;
    };

    // ---- compute decode: wave -> 32x32 quadrant (2 M-tiles x 2 N-tiles)
    const int w  = tid >> 6;
    const int mp = (w >> 1) * 2;   // 0 or 2
    const int np = (w & 1) * 2;    // 0 or 2

    f32x4 acc00 = {0.f, 0.f, 0.f, 0.f};
    f32x4 acc01 = {0.f, 0.f, 0.f, 0.f};
    f32x4 acc10 = {0.f, 0.f, 0.f, 0.f};
    f32x4 acc11 = {0.f, 0.f, 0.f, 0.f};

    auto frag = [&](const unsigned char* plane, int tile, int c) -> short8 {
        return __builtin_bit_cast(short8,
            *reinterpret_cast<const uint4*>(plane + ((tile * 2 + c) * 64 + lane) * 16));
    };

    auto compute = [&](int b) {
        const unsigned char* base = smem + b * 32768;
#pragma unroll
        for (int c = 0; c < 2; ++c) {
            short8 ah0 = frag(base +     0, mp + 0, c);
            short8 ah1 = frag(base +     0, mp + 1, c);
            short8 al0 = frag(base +  8192, mp + 0, c);
            short8 al1 = frag(base +  8192, mp + 1, c);
            short8 bh0 = frag(base + 16384, np + 0, c);
            short8 bh1 = frag(base + 16384, np + 1, c);
            short8 bl0 = frag(base + 24576, np + 0, c);
            short8 bl1 = frag(base + 24576, np + 1, c);
            // hi*hi
            acc00 = MFMA(ah0, bh0, acc00);
            acc01 = MFMA(ah0, bh1, acc01);
            acc10 = MFMA(ah1, bh0, acc10);
            acc11 = MFMA(ah1, bh1, acc11);
            // hi*lo
            acc00 = MFMA(ah0, bl0, acc00);
            acc01 = MFMA(ah0, bl1, acc01);
            acc10 = MFMA(ah1, bl0, acc10);
            acc11 = MFMA(ah1, bl1, acc11);
            // lo*hi
            acc00 = MFMA(al0, bh0, acc00);
            acc01 = MFMA(al0, bh1, acc01);
            acc10 = MFMA(al1, bh0, acc10);
            acc11 = MFMA(al1, bh1, acc11);
        }
    };

    // ---- pipelined main loop: 1 barrier per chunk, loads prefetched 1 chunk ahead
    load_regs(0);
    write_buf(0);
    __syncthreads();
    int cur = 0;
    for (int t = 0; t < NCHUNK; ++t) {
        if (t + 1 < NCHUNK) load_regs((t + 1) * BK);
        compute(cur);                              // reads buf[cur]
        if (t + 1 < NCHUNK) write_buf(cur ^ 1);    // writes other buffer (no hazard)
        __syncthreads();
        cur ^= 1;
    }

    // ---- epilogue: logits tile to LDS, then top-2 per token
    float* L = reinterpret_cast<float*>(smem);   // [64][68] fp32
    {
        const f32x4 av[2][2] = {{acc00, acc01}, {acc10, acc11}};
#pragma unroll
        for (int mi = 0; mi < 2; ++mi) {
#pragma unroll
            for (int ni = 0; ni < 2; ++ni) {
                const int trow = (mp + mi) * 16 + (lane >> 4) * 4;
                const int ecol = (np + ni) * 16 + (lane & 15);
#pragma unroll
                for (int r = 0; r < 4; ++r) {
                    L[(trow + r) * 68 + ecol] = av[mi][ni][r];
                }
            }
        }
    }
    __syncthreads();

    if (tid < BM) {
        const float* row = &L[tid * 68];
        float best1 = -INFINITY, best2 = -INFINITY;
        int i1 = 0, i2 = 0;
#pragma unroll
        for (int e = 0; e < NUM_EXPERTS; ++e) {
            float v = row[e];
            if (v > best1) {
                best2 = best1; i2 = i1;
                best1 = v;     i1 = e;
            } else if (v > best2) {
                best2 = v; i2 = e;
            }
        }
        const int t = tok0 + tid;
        out[(size_t)t * 2 + 0] = best1;
        out[(size_t)t * 2 + 1] = best2;
        out[(size_t)T_TOKENS * 2 + (size_t)t * 2 + 0] = (float)i1;
        out[(size_t)T_TOKENS * 2 + (size_t)t * 2 + 1] = (float)i2;
    }
}

extern "C" void kernel_launch(void* const* d_in, const int* in_sizes, int n_in,
                              void* d_out, int out_size, void* d_ws, size_t ws_size,
                              hipStream_t stream) {
    const float* A = (const float*)d_in[0];   // hidden_states [4,4096,4096] fp32
    const float* W = (const float*)d_in[1];   // W [64,4096] fp32
    float* out = (float*)d_out;

    dim3 grid(T_TOKENS / BM);   // 256 blocks
    dim3 block(256);
    router_mfma_topk<<<grid, block, 0, stream>>>(A, W, out);
}

// Round 4
// 108.035 us; speedup vs baseline: 1.8307x; 1.4038x over previous
//
#include <hip/hip_runtime.h>
#include <hip/hip_bf16.h>
#include <math.h>

#define NUM_EXPERTS 64
#define HIDDEN      4096
#define T_TOKENS    16384   // B*S
#define NCHUNK      128     // K chunks of 32

using short8 = __attribute__((ext_vector_type(8))) short;   // 8 bf16
using f32x4  = __attribute__((ext_vector_type(4))) float;

// f32 -> bf16 bits, round-to-nearest-even, pure integer ops.
__device__ __forceinline__ unsigned bf16_rn(float f) {
    unsigned u = __builtin_bit_cast(unsigned, f);
    return (u + 0x7fffu + ((u >> 16) & 1u)) >> 16;
}
// (f0,f1) -> packed bf16 hi (f0 low 16) + packed bf16 lo residuals.
__device__ __forceinline__ unsigned pack_pair(float f0, float f1, unsigned& lopk) {
    unsigned h0b = bf16_rn(f0), h1b = bf16_rn(f1);
    float h0 = __builtin_bit_cast(float, h0b << 16);
    float h1 = __builtin_bit_cast(float, h1b << 16);
    lopk = bf16_rn(f0 - h0) | (bf16_rn(f1 - h1) << 16);
    return h0b | (h1b << 16);
}
// 8 consecutive floats -> 16B hi plane + 16B lo plane
__device__ __forceinline__ void split8(const float4 a, const float4 b, uint4& hi, uint4& lo) {
    hi.x = pack_pair(a.x, a.y, lo.x);
    hi.y = pack_pair(a.z, a.w, lo.y);
    hi.z = pack_pair(b.x, b.y, lo.z);
    hi.w = pack_pair(b.z, b.w, lo.w);
}

#define MFMA(a, b, c) __builtin_amdgcn_mfma_f32_16x16x32_bf16((a), (b), (c), 0, 0, 0)

// ---- pre-kernel: split W [64][4096] f32 into fragment-ordered bf16 hi/lo planes.
// Fragment j = ((t*4 + nt)*64 + lane): lane holds W[e = nt*16 + (lane&15)]
// [k = t*32 + (lane>>4)*8 .. +8].  hi at ws[j*16], lo at ws + 512KB + j*16.
__global__ __launch_bounds__(256) void w_split_kernel(
    const float* __restrict__ W, unsigned char* __restrict__ ws)
{
    const int j  = blockIdx.x * 256 + threadIdx.x;   // 0..32767
    const int l  = j & 63;
    const int nt = (j >> 6) & 3;
    const int t  = j >> 8;
    const int e  = nt * 16 + (l & 15);
    const int k0 = t * 32 + ((l >> 4) & 3) * 8;
    const float* p = W + (size_t)e * HIDDEN + k0;
    float4 w0 = *reinterpret_cast<const float4*>(p);
    float4 w1 = *reinterpret_cast<const float4*>(p + 4);
    uint4 hi, lo;
    split8(w0, w1, hi, lo);
    *reinterpret_cast<uint4*>(ws + (size_t)j * 16)            = hi;
    *reinterpret_cast<uint4*>(ws + 524288 + (size_t)j * 16)   = lo;
}

// ---- main kernel: 1 wave = 16 tokens x 64 experts, no LDS, no barriers.
#define LOAD_A(dst, g_) do {                                                   \
    const float* pA_ = aBase + (size_t)(g_) * 128;                             \
    _Pragma("unroll")                                                          \
    for (int u_ = 0; u_ < 4; ++u_) {                                           \
        dst[u_][0] = *reinterpret_cast<const float4*>(pA_ + u_ * 32);          \
        dst[u_][1] = *reinterpret_cast<const float4*>(pA_ + u_ * 32 + 4);      \
    } } while (0)

#define LOAD_W(dst, t_) do {                                                   \
    const unsigned char* pW_ = wsHi + (size_t)(t_) * 4096 + laneOff;           \
    _Pragma("unroll")                                                          \
    for (int nt_ = 0; nt_ < 4; ++nt_) {                                        \
        dst[nt_]     = *reinterpret_cast<const uint4*>(pW_ + nt_ * 1024);      \
        dst[nt_ + 4] = *reinterpret_cast<const uint4*>(pW_ + 524288 + nt_ * 1024); \
    } } while (0)

#define CHUNK(ab_, u_, wb_) do {                                               \
    uint4 hi_, lo_;                                                            \
    split8(ab_[u_][0], ab_[u_][1], hi_, lo_);                                  \
    short8 ah_ = __builtin_bit_cast(short8, hi_);                              \
    short8 al_ = __builtin_bit_cast(short8, lo_);                              \
    _Pragma("unroll")                                                          \
    for (int nt_ = 0; nt_ < 4; ++nt_) {                                        \
        short8 wh_ = __builtin_bit_cast(short8, wb_[nt_]);                     \
        short8 wl_ = __builtin_bit_cast(short8, wb_[nt_ + 4]);                 \
        acc[nt_] = MFMA(ah_, wh_, acc[nt_]);                                   \
        acc[nt_] = MFMA(ah_, wl_, acc[nt_]);                                   \
        acc[nt_] = MFMA(al_, wh_, acc[nt_]);                                   \
    } } while (0)

__global__ __launch_bounds__(256, 1) void router_mfma_topk(
    const float* __restrict__ A,
    const unsigned char* __restrict__ wsHi,   // frag-ordered W hi; lo at +512KB
    float* __restrict__ out)
{
    const int tid  = threadIdx.x;
    const int lane = tid & 63;
    const int tok0 = blockIdx.x * 64 + (tid >> 6) * 16;

    const float* aBase = A + (size_t)(tok0 + (lane & 15)) * HIDDEN + ((lane >> 4) & 3) * 8;
    const int laneOff = lane * 16;

    f32x4 acc[4];
#pragma unroll
    for (int nt = 0; nt < 4; ++nt) acc[nt] = (f32x4){0.f, 0.f, 0.f, 0.f};

    float4 aA[4][2], aB[4][2];
    uint4  wA[8], wB[8];

    LOAD_A(aA, 0);
    LOAD_W(wA, 0);

    for (int gp = 0; gp < 16; ++gp) {
        const int t0 = gp * 8;
        LOAD_A(aB, 2 * gp + 1);                 // A for chunks t0+4..t0+7
        LOAD_W(wB, t0 + 1);  CHUNK(aA, 0, wA);
        LOAD_W(wA, t0 + 2);  CHUNK(aA, 1, wB);
        LOAD_W(wB, t0 + 3);  CHUNK(aA, 2, wA);
        LOAD_W(wA, t0 + 4);  CHUNK(aA, 3, wB);
        if (gp < 15) LOAD_A(aA, 2 * gp + 2);    // A for next iter chunks
        LOAD_W(wB, t0 + 5);  CHUNK(aB, 0, wA);
        LOAD_W(wA, t0 + 6);  CHUNK(aB, 1, wB);
        LOAD_W(wB, t0 + 7);  CHUNK(aB, 2, wA);
        if (gp < 15) LOAD_W(wA, t0 + 8);
        CHUNK(aB, 3, wB);
    }

    // ---- epilogue: all-register top-2. Lane holds C rows (lane>>4)*4+r,
    // col nt*16 + (lane&15).  Reduce across the 16 lanes of each row group.
    const int eBase = lane & 15;
#pragma unroll
    for (int r = 0; r < 4; ++r) {
        float b1 = acc[0][r]; int i1 = eBase;
        float b2 = -INFINITY; int i2 = 0;
#pragma unroll
        for (int nt = 1; nt < 4; ++nt) {
            float v = acc[nt][r];
            int   e = nt * 16 + eBase;
            if (v > b1)      { b2 = b1; i2 = i1; b1 = v; i1 = e; }
            else if (v > b2) { b2 = v;  i2 = e; }
        }
#pragma unroll
        for (int m = 1; m <= 8; m <<= 1) {
            float o1 = __shfl_xor(b1, m); int oi1 = __shfl_xor(i1, m);
            float o2 = __shfl_xor(b2, m); int oi2 = __shfl_xor(i2, m);
            float n1, c, n2; int ni1, ci, ni2;
            if (o1 > b1 || (o1 == b1 && oi1 < i1)) { n1 = o1; ni1 = oi1; c = b1; ci = i1; }
            else                                   { n1 = b1; ni1 = i1;  c = o1; ci = oi1; }
            if (b2 > o2 || (b2 == o2 && i2 < oi2)) { n2 = b2; ni2 = i2; }
            else                                   { n2 = o2; ni2 = oi2; }
            if (c > n2 || (c == n2 && ci < ni2))   { n2 = c;  ni2 = ci; }
            b1 = n1; i1 = ni1; b2 = n2; i2 = ni2;
        }
        if ((lane & 15) == 0) {
            const int tok = tok0 + (lane >> 4) * 4 + r;
            out[(size_t)tok * 2 + 0] = b1;
            out[(size_t)tok * 2 + 1] = b2;
            out[(size_t)2 * T_TOKENS + (size_t)tok * 2 + 0] = (float)i1;
            out[(size_t)2 * T_TOKENS + (size_t)tok * 2 + 1] = (float)i2;
        }
    }
}

extern "C" void kernel_launch(void* const* d_in, const int* in_sizes, int n_in,
                              void* d_out, int out_size, void* d_ws, size_t ws_size,
                              hipStream_t stream) {
    const float* A = (const float*)d_in[0];   // hidden_states fp32 [16384,4096]
    const float* W = (const float*)d_in[1];   // W fp32 [64,4096]
    float* out = (float*)d_out;
    unsigned char* ws = (unsigned char*)d_ws; // needs 1 MB (hi 512K + lo 512K)

    w_split_kernel<<<dim3(128), dim3(256), 0, stream>>>(W, ws);
    router_mfma_topk<<<dim3(T_TOKENS / 64), dim3(256), 0, stream>>>(A, ws, out);
}

// Round 5
// 85.548 us; speedup vs baseline: 2.3119x; 1.2629x over previous
//
#include <hip/hip_runtime.h>
#include <hip/hip_bf16.h>
#include <math.h>

#define NUM_EXPERTS 64
#define HIDDEN      4096
#define T_TOKENS    16384   // B*S

using short8 = __attribute__((ext_vector_type(8))) short;   // 8 bf16
using f32x4  = __attribute__((ext_vector_type(4))) float;

// f32 -> bf16 bits, round-to-nearest-even, pure integer ops.
__device__ __forceinline__ unsigned bf16_rn(float f) {
    unsigned u = __builtin_bit_cast(unsigned, f);
    return (u + 0x7fffu + ((u >> 16) & 1u)) >> 16;
}
// (f0,f1) -> packed bf16 hi (f0 low 16) + packed bf16 lo residuals.
__device__ __forceinline__ unsigned pack_pair(float f0, float f1, unsigned& lopk) {
    unsigned h0b = bf16_rn(f0), h1b = bf16_rn(f1);
    float h0 = __builtin_bit_cast(float, h0b << 16);
    float h1 = __builtin_bit_cast(float, h1b << 16);
    lopk = bf16_rn(f0 - h0) | (bf16_rn(f1 - h1) << 16);
    return h0b | (h1b << 16);
}
// 8 consecutive floats -> 16B hi plane + 16B lo plane
__device__ __forceinline__ void split8(const float4 a, const float4 b, uint4& hi, uint4& lo) {
    hi.x = pack_pair(a.x, a.y, lo.x);
    hi.y = pack_pair(a.z, a.w, lo.y);
    hi.z = pack_pair(b.x, b.y, lo.z);
    hi.w = pack_pair(b.z, b.w, lo.w);
}

#define MFMA(a, b, c) __builtin_amdgcn_mfma_f32_16x16x32_bf16((a), (b), (c), 0, 0, 0)

// ---- pre-kernel: split W [64][4096] f32 into fragment-ordered bf16 hi/lo planes.
// Fragment j = ((t*4 + nt)*64 + lane): lane holds W[e = nt*16 + (lane&15)]
// [k = t*32 + (lane>>4)*8 .. +8].  hi at ws[j*16], lo at ws + 512KB + j*16.
__global__ __launch_bounds__(256) void w_split_kernel(
    const float* __restrict__ W, unsigned char* __restrict__ ws)
{
    const int j  = blockIdx.x * 256 + threadIdx.x;   // 0..32767
    const int l  = j & 63;
    const int nt = (j >> 6) & 3;
    const int t  = j >> 8;
    const int e  = nt * 16 + (l & 15);
    const int k0 = t * 32 + ((l >> 4) & 3) * 8;
    const float* p = W + (size_t)e * HIDDEN + k0;
    float4 w0 = *reinterpret_cast<const float4*>(p);
    float4 w1 = *reinterpret_cast<const float4*>(p + 4);
    uint4 hi, lo;
    split8(w0, w1, hi, lo);
    *reinterpret_cast<uint4*>(ws + (size_t)j * 16)            = hi;
    *reinterpret_cast<uint4*>(ws + 524288 + (size_t)j * 16)   = lo;
}

// ---- main kernel: block = 16 tokens; 4 waves K-split (1024 k each); LDS combine.
#define LOAD_A(dst, g_) do {                                                   \
    const float* pA_ = aBase + (size_t)(g_) * 128;                             \
    _Pragma("unroll")                                                          \
    for (int u_ = 0; u_ < 4; ++u_) {                                           \
        dst[u_][0] = *reinterpret_cast<const float4*>(pA_ + u_ * 32);          \
        dst[u_][1] = *reinterpret_cast<const float4*>(pA_ + u_ * 32 + 4);      \
    } } while (0)

#define LOAD_W(dst, t_) do {                                                   \
    const unsigned char* pW_ = wsHi + (size_t)(tBase + (t_)) * 4096 + laneOff; \
    _Pragma("unroll")                                                          \
    for (int nt_ = 0; nt_ < 4; ++nt_) {                                        \
        dst[nt_]     = *reinterpret_cast<const uint4*>(pW_ + nt_ * 1024);      \
        dst[nt_ + 4] = *reinterpret_cast<const uint4*>(pW_ + 524288 + nt_ * 1024); \
    } } while (0)

#define CHUNK(ab_, u_, wb_) do {                                               \
    uint4 hi_, lo_;                                                            \
    split8(ab_[u_][0], ab_[u_][1], hi_, lo_);                                  \
    short8 ah_ = __builtin_bit_cast(short8, hi_);                              \
    short8 al_ = __builtin_bit_cast(short8, lo_);                              \
    _Pragma("unroll")                                                          \
    for (int nt_ = 0; nt_ < 4; ++nt_) {                                        \
        short8 wh_ = __builtin_bit_cast(short8, wb_[nt_]);                     \
        short8 wl_ = __builtin_bit_cast(short8, wb_[nt_ + 4]);                 \
        acc[nt_] = MFMA(ah_, wh_, acc[nt_]);                                   \
        acc[nt_] = MFMA(ah_, wl_, acc[nt_]);                                   \
        acc[nt_] = MFMA(al_, wh_, acc[nt_]);                                   \
    } } while (0)

__global__ __launch_bounds__(256, 3) void router_mfma_topk(
    const float* __restrict__ A,
    const unsigned char* __restrict__ wsHi,   // frag-ordered W hi; lo at +512KB
    float* __restrict__ out)
{
    __shared__ f32x4 part[4][4][64];          // 16 KB: [wave][nt][lane]

    const int tid  = threadIdx.x;
    const int lane = tid & 63;
    const int w    = tid >> 6;                // wave id = K-quarter
    const int tok0 = blockIdx.x * 16;
    const int tBase = w * 32;                 // global chunk base (chunks of K=32)

    const float* aBase = A + (size_t)(tok0 + (lane & 15)) * HIDDEN
                           + w * 1024 + ((lane >> 4) & 3) * 8;
    const int laneOff = lane * 16;

    f32x4 acc[4];
#pragma unroll
    for (int nt = 0; nt < 4; ++nt) acc[nt] = (f32x4){0.f, 0.f, 0.f, 0.f};

    float4 aA[4][2], aB[4][2];
    uint4  wA[8], wB[8];

    LOAD_A(aA, 0);
    LOAD_W(wA, 0);

    for (int gp = 0; gp < 4; ++gp) {          // 4 x 8 chunks = 32 chunks = 1024 k
        const int t0 = gp * 8;
        LOAD_A(aB, 2 * gp + 1);
        LOAD_W(wB, t0 + 1);  CHUNK(aA, 0, wA);
        LOAD_W(wA, t0 + 2);  CHUNK(aA, 1, wB);
        LOAD_W(wB, t0 + 3);  CHUNK(aA, 2, wA);
        LOAD_W(wA, t0 + 4);  CHUNK(aA, 3, wB);
        if (gp < 3) LOAD_A(aA, 2 * gp + 2);
        LOAD_W(wB, t0 + 5);  CHUNK(aB, 0, wA);
        LOAD_W(wA, t0 + 6);  CHUNK(aB, 1, wB);
        LOAD_W(wB, t0 + 7);  CHUNK(aB, 2, wA);
        if (gp < 3) LOAD_W(wA, t0 + 8);
        CHUNK(aB, 3, wB);
    }

    // ---- combine K-quarters via LDS ----
#pragma unroll
    for (int nt = 0; nt < 4; ++nt) part[w][nt][lane] = acc[nt];
    __syncthreads();

    if (w == 0) {
#pragma unroll
        for (int nt = 0; nt < 4; ++nt) {
            acc[nt] = acc[nt] + part[1][nt][lane] + part[2][nt][lane] + part[3][nt][lane];
        }

        // ---- all-register top-2: lane holds rows (lane>>4)*4+r, col nt*16+(lane&15)
        const int eBase = lane & 15;
#pragma unroll
        for (int r = 0; r < 4; ++r) {
            float b1 = acc[0][r]; int i1 = eBase;
            float b2 = -INFINITY; int i2 = 0;
#pragma unroll
            for (int nt = 1; nt < 4; ++nt) {
                float v = acc[nt][r];
                int   e = nt * 16 + eBase;
                if (v > b1)      { b2 = b1; i2 = i1; b1 = v; i1 = e; }
                else if (v > b2) { b2 = v;  i2 = e; }
            }
#pragma unroll
            for (int m = 1; m <= 8; m <<= 1) {
                float o1 = __shfl_xor(b1, m); int oi1 = __shfl_xor(i1, m);
                float o2 = __shfl_xor(b2, m); int oi2 = __shfl_xor(i2, m);
                float n1, c, n2; int ni1, ci, ni2;
                if (o1 > b1 || (o1 == b1 && oi1 < i1)) { n1 = o1; ni1 = oi1; c = b1; ci = i1; }
                else                                   { n1 = b1; ni1 = i1;  c = o1; ci = oi1; }
                if (b2 > o2 || (b2 == o2 && i2 < oi2)) { n2 = b2; ni2 = i2; }
                else                                   { n2 = o2; ni2 = oi2; }
                if (c > n2 || (c == n2 && ci < ni2))   { n2 = c;  ni2 = ci; }
                b1 = n1; i1 = ni1; b2 = n2; i2 = ni2;
            }
            if ((lane & 15) == 0) {
                const int tok = tok0 + (lane >> 4) * 4 + r;
                out[(size_t)tok * 2 + 0] = b1;
                out[(size_t)tok * 2 + 1] = b2;
                out[(size_t)2 * T_TOKENS + (size_t)tok * 2 + 0] = (float)i1;
                out[(size_t)2 * T_TOKENS + (size_t)tok * 2 + 1] = (float)i2;
            }
        }
    }
}

extern "C" void kernel_launch(void* const* d_in, const int* in_sizes, int n_in,
                              void* d_out, int out_size, void* d_ws, size_t ws_size,
                              hipStream_t stream) {
    const float* A = (const float*)d_in[0];   // hidden_states fp32 [16384,4096]
    const float* W = (const float*)d_in[1];   // W fp32 [64,4096]
    float* out = (float*)d_out;
    unsigned char* ws = (unsigned char*)d_ws; // 1 MB used (hi 512K + lo 512K)

    w_split_kernel<<<dim3(128), dim3(256), 0, stream>>>(W, ws);
    router_mfma_topk<<<dim3(T_TOKENS / 16), dim3(256), 0, stream>>>(A, ws, out);
}